// Round 23
// baseline (729.932 us; speedup 1.0000x reference)
//
#include <hip/hip_runtime.h>
#include <hip/hip_bf16.h>
#include <math.h>

#define B_TOK 8192
#define DDIM  1024
#define HDIM  4096
#define NEXP  8
#define CAP   17408   // 16384 routed pairs + 8*127 padding (128-tile)

typedef unsigned short u16;
using f32x4  = __attribute__((ext_vector_type(4))) float;
using bf16x8 = __attribute__((ext_vector_type(8))) short;  // 8 bf16 in 4 VGPRs
using u16x8  = __attribute__((ext_vector_type(8))) unsigned short;

__device__ __forceinline__ u16 f2bf(float f) {
  union { float f; unsigned u; } v; v.f = f;
  unsigned r = v.u + 0x7FFFu + ((v.u >> 16) & 1u);  // RNE
  return (u16)(r >> 16);
}

__device__ __forceinline__ void load_lds16(const void* g, void* l) {
  __builtin_amdgcn_global_load_lds((const __attribute__((address_space(1))) void*)g,
                                   (__attribute__((address_space(3))) void*)l,
                                   16, 0, 0);
}

// ---- W1+W2 f32->bf16, m13 shape: 2048 blocks, deep grid-stride, NO branches.
// 8.39M u16x8 chunks / 524288 threads = exactly 16 per thread; it<8 -> W1,
// it>=8 -> W2 (compile-time after unroll -> two clean pipelined streams).
__global__ __launch_bounds__(256) void cvtw_kernel(
    const float* __restrict__ w1, const float* __restrict__ w2,
    u16* __restrict__ w1b, u16* __restrict__ w2b)
{
  const int gtid = blockIdx.x * 256 + threadIdx.x;   // [0, 524288)
  const int TCNT = 2048 * 256;
  const f32x4* s1 = (const f32x4*)w1;
  const f32x4* s2 = (const f32x4*)w2;
  u16x8* d1 = (u16x8*)w1b;
  u16x8* d2 = (u16x8*)w2b;
#pragma unroll 4
  for (int it = 0; it < 16; ++it) {
    const bool first = (it < 8);
    const int  i     = (first ? it : it - 8) * TCNT + gtid;
    const f32x4* src = first ? s1 : s2;
    u16x8*       dst = first ? d1 : d2;
    f32x4 a = src[2 * i];
    f32x4 b = src[2 * i + 1];
    u16x8 v;
    v[0] = f2bf(a[0]); v[1] = f2bf(a[1]); v[2] = f2bf(a[2]); v[3] = f2bf(a[3]);
    v[4] = f2bf(b[0]); v[5] = f2bf(b[1]); v[6] = f2bf(b[2]); v[7] = f2bf(b[3]);
    dst[i] = v;
  }
}

// ------- gating: logits (f64 accum), top-2, softmax;  fused X->bf16 cvt -------
__global__ __launch_bounds__(256) void gate_kernel(
    const float* __restrict__ inp, const float* __restrict__ gw,
    const float* __restrict__ gb, int* __restrict__ tok_e,
    float* __restrict__ tok_g, int* __restrict__ counts,
    ushort4* __restrict__ Xb4)
{
  int gtid = blockIdx.x * 256 + threadIdx.x;
  int tok  = gtid >> 6;
  int lane = threadIdx.x & 63;
  if (tok >= B_TOK) return;
  const float4* X = (const float4*)(inp + (size_t)tok * DDIM);
  float4 x[4];
#pragma unroll
  for (int j = 0; j < 4; ++j) x[j] = X[j * 64 + lane];
  ushort4* Xrow = Xb4 + (size_t)tok * (DDIM / 4);
#pragma unroll
  for (int j = 0; j < 4; ++j) {
    ushort4 o;
    o.x = f2bf(x[j].x); o.y = f2bf(x[j].y); o.z = f2bf(x[j].z); o.w = f2bf(x[j].w);
    Xrow[j * 64 + lane] = o;
  }
  float lg[NEXP];
#pragma unroll
  for (int e = 0; e < NEXP; ++e) {
    const float4* W = (const float4*)(gw + e * DDIM);
    double s = 0.0;
#pragma unroll
    for (int j = 0; j < 4; ++j) {
      float4 w = W[j * 64 + lane];
      s += (double)x[j].x * w.x + (double)x[j].y * w.y
         + (double)x[j].z * w.z + (double)x[j].w * w.w;
    }
#pragma unroll
    for (int o = 32; o > 0; o >>= 1) s += __shfl_xor(s, o);
    lg[e] = (float)(s + (double)gb[e]);
  }
  if (lane == 0) {
    int i0 = 0; float v0 = lg[0];
#pragma unroll
    for (int e = 1; e < NEXP; ++e) if (lg[e] > v0) { v0 = lg[e]; i0 = e; }
    int i1 = -1; float v1 = -3.4e38f;
#pragma unroll
    for (int e = 0; e < NEXP; ++e) if (e != i0 && lg[e] > v1) { v1 = lg[e]; i1 = e; }
    float t   = __expf(v1 - v0);
    float inv = 1.0f / (1.0f + t);
    tok_e[2 * tok] = i0; tok_e[2 * tok + 1] = i1;
    tok_g[2 * tok] = inv; tok_g[2 * tok + 1] = t * inv;
    atomicAdd(&counts[i0], 1);
    atomicAdd(&counts[i1], 1);
  }
}

// -- scatter tokens into expert slots (scan fused; writes inverse map tok_slot) --
__global__ __launch_bounds__(256) void scatter_kernel(
    const int* __restrict__ tok_e, const float* __restrict__ tok_g,
    const int* __restrict__ counts, int* __restrict__ cursors,
    int* __restrict__ slot_token, float* __restrict__ slot_gate,
    int* __restrict__ tok_slot,
    int* __restrict__ offs, int* __restrict__ padded)
{
  __shared__ int soffs[NEXP];
  if (threadIdx.x == 0) {
    int off = 0;
    for (int e = 0; e < NEXP; ++e) {
      soffs[e] = off;
      int p = (counts[e] + 127) & ~127;
      off += p;
      if (blockIdx.x == 0) { offs[e] = soffs[e]; padded[e] = p; }
    }
  }
  __syncthreads();
  int b = blockIdx.x * 256 + threadIdx.x;
  if (b >= B_TOK) return;
#pragma unroll
  for (int k = 0; k < 2; ++k) {
    int e   = tok_e[2 * b + k];
    float g = tok_g[2 * b + k];
    int pos = atomicAdd(&cursors[e], 1);
    int s   = soffs[e] + pos;
    slot_token[s] = b;
    slot_gate[s]  = g;
    tok_slot[2 * b + k] = s;
  }
}

// ===== 128x128 x BK64, SINGLE LDS buffer, 8-slot XOR swizzle (bf16 weights) =====
#define STAGE(kt_) do {                                                   \
    _Pragma("unroll") for (int g = 0; g < 4; ++g) {                       \
      load_lds16(pAg[g] + (kt_) * 64, &As[(g * 256 + tid) * 8]);           \
      load_lds16(pBg[g] + (kt_) * 64, &Bs[(g * 256 + tid) * 8]);           \
    } } while (0)

#define GEMM_BODY(NT_) do {                                               \
    const int NT = (NT_);                                                 \
    _Pragma("unroll 1")                                                   \
    for (int t = 0; t < NT; ++t) {                                        \
      STAGE(t);                                                           \
      __syncthreads();                                                    \
      bf16x8 af[4][2], bfr[4][2];                                         \
      _Pragma("unroll") for (int m = 0; m < 4; ++m)                       \
        _Pragma("unroll") for (int kk = 0; kk < 2; ++kk)                  \
          af[m][kk] = *(const bf16x8*)&As[(wm + m*16 + fr)*64             \
                                        + (((kk*4 + fq) ^ fr7) * 8)];     \
      _Pragma("unroll") for (int n = 0; n < 4; ++n)                       \
        _Pragma("unroll") for (int kk = 0; kk < 2; ++kk)                  \
          bfr[n][kk] = *(const bf16x8*)&Bs[(wn + n*16 + fr)*64            \
                                        + (((kk*4 + fq) ^ fr7) * 8)];     \
      _Pragma("unroll") for (int kk = 0; kk < 2; ++kk)                    \
      _Pragma("unroll") for (int m = 0; m < 4; ++m)                       \
      _Pragma("unroll") for (int n = 0; n < 4; ++n)                       \
        acc[m][n] = __builtin_amdgcn_mfma_f32_16x16x32_bf16(              \
            af[m][kk], bfr[n][kk], acc[m][n], 0, 0, 0);                   \
      __syncthreads();                                                    \
    } } while (0)

// ---------------- GEMM1: h = relu(X_gather @ W1[e]^T + b1[e]) -> bf16 ----------------
__global__ __launch_bounds__(256, 4) void gemm1_kernel(
    const u16* __restrict__ Xb, const u16* __restrict__ W1b,
    const float* __restrict__ b1, const int* __restrict__ slot_token,
    const int* __restrict__ offs, const int* __restrict__ padded,
    u16* __restrict__ Hb)
{
  const int h   = blockIdx.x + 32 * (blockIdx.y + 64 * blockIdx.z);  // grid (32,64,8)
  const int e   = h & 7;          // XCD id == expert
  const int r   = h >> 3;
  const int mi  = r >> 5;         // m-tile [0,64)
  const int nti = r & 31;         // n-tile fastest within XCD
  if (mi * 128 >= padded[e]) return;
  const int base_slot = offs[e] + mi * 128;
  const int n0 = nti * 128;

  __shared__ __align__(16) u16 As[8192];   // 128 x 64
  __shared__ __align__(16) u16 Bs[8192];
  __shared__ int toks[128];

  const int tid = threadIdx.x;
  if (tid < 128) toks[tid] = slot_token[base_slot + tid];
  __syncthreads();

  const u16* pAg[4];
  const u16* pBg[4];
#pragma unroll
  for (int g = 0; g < 4; ++g) {
    int i = g * 256 + tid, rr = i >> 3, sl = i & 7;
    int kc = (sl ^ (rr & 7)) * 8;
    pAg[g] = Xb + (size_t)toks[rr] * DDIM + kc;
    pBg[g] = W1b + ((size_t)e * HDIM + (size_t)(n0 + rr)) * DDIM + kc;
  }

  const int wave = tid >> 6, lane = tid & 63;
  const int wm = (wave >> 1) * 64, wn = (wave & 1) * 64;
  const int fr = lane & 15, fq = lane >> 4, fr7 = fr & 7;

  f32x4 acc[4][4];
#pragma unroll
  for (int m = 0; m < 4; ++m)
#pragma unroll
    for (int n = 0; n < 4; ++n) acc[m][n] = f32x4{0.f, 0.f, 0.f, 0.f};

  GEMM_BODY(DDIM / 64);   // 16 bodies

#pragma unroll
  for (int n = 0; n < 4; ++n) {
    int col = n0 + wn + n * 16 + fr;
    float bias = b1[e * HDIM + col];
#pragma unroll
    for (int m = 0; m < 4; ++m) {
      int row0 = wm + m * 16 + fq * 4;
#pragma unroll
      for (int j = 0; j < 4; ++j) {
        float v = acc[m][n][j] + bias;
        v = v > 0.f ? v : 0.f;
        Hb[(size_t)(base_slot + row0 + j) * HDIM + col] = f2bf(v);
      }
    }
  }
}

// --- GEMM2: P[slot] = gate*exp(relu(H @ W2[e]^T + b2[e]))  (plain stores) ---
__global__ __launch_bounds__(256, 4) void gemm2_kernel(
    const u16* __restrict__ Hb, const u16* __restrict__ W2b,
    const float* __restrict__ b2, const float* __restrict__ slot_gate,
    const int* __restrict__ offs, const int* __restrict__ padded,
    float* __restrict__ P)
{
  const int h   = blockIdx.x + 8 * (blockIdx.y + 64 * blockIdx.z);  // grid (8,64,8)
  const int e   = h & 7;
  const int r   = h >> 3;
  const int mi  = r >> 3;         // m-tile [0,64)
  const int nti = r & 7;          // n-tile fastest within XCD
  if (mi * 128 >= padded[e]) return;
  const int base_slot = offs[e] + mi * 128;
  const int n0 = nti * 128;

  __shared__ __align__(16) u16 As[8192];
  __shared__ __align__(16) u16 Bs[8192];
  __shared__ float gts[128];

  const int tid = threadIdx.x;
  if (tid < 128) gts[tid] = slot_gate[base_slot + tid];
  __syncthreads();

  const u16* pAg[4];
  const u16* pBg[4];
#pragma unroll
  for (int g = 0; g < 4; ++g) {
    int i = g * 256 + tid, rr = i >> 3, sl = i & 7;
    int kc = (sl ^ (rr & 7)) * 8;
    pAg[g] = Hb + (size_t)(base_slot + rr) * HDIM + kc;
    pBg[g] = W2b + ((size_t)e * DDIM + (size_t)(n0 + rr)) * HDIM + kc;
  }

  const int wave = tid >> 6, lane = tid & 63;
  const int wm = (wave >> 1) * 64, wn = (wave & 1) * 64;
  const int fr = lane & 15, fq = lane >> 4, fr7 = fr & 7;

  f32x4 acc[4][4];
#pragma unroll
  for (int m = 0; m < 4; ++m)
#pragma unroll
    for (int n = 0; n < 4; ++n) acc[m][n] = f32x4{0.f, 0.f, 0.f, 0.f};

  GEMM_BODY(HDIM / 64);   // 64 bodies

#pragma unroll
  for (int n = 0; n < 4; ++n) {
    int col = n0 + wn + n * 16 + fr;
    float bias = b2[e * DDIM + col];
#pragma unroll
    for (int m = 0; m < 4; ++m) {
      int row0 = wm + m * 16 + fq * 4;
#pragma unroll
      for (int j = 0; j < 4; ++j) {
        int row = row0 + j;
        float v = acc[m][n][j] + bias;
        v = v > 0.f ? v : 0.f;
        P[(size_t)(base_slot + row) * DDIM + col] = gts[row] * __expf(v);
      }
    }
  }
}

// ------- combine: out[tok] = log(P[s0] + P[s1] + eps)  (fixed k-order sum) -------
__global__ __launch_bounds__(256) void combine_kernel(
    const float4* __restrict__ P4, const int* __restrict__ tok_slot,
    float4* __restrict__ out4)
{
  const float EPS = 2.220446049250313e-16f;
  const int total = B_TOK * (DDIM / 4);
  for (int i = blockIdx.x * 256 + threadIdx.x; i < total; i += gridDim.x * 256) {
    int tok = i >> 8, d4 = i & 255;
    int s0 = tok_slot[2 * tok], s1 = tok_slot[2 * tok + 1];
    float4 a = P4[(size_t)s0 * (DDIM / 4) + d4];
    float4 b = P4[(size_t)s1 * (DDIM / 4) + d4];
    float4 v;
    v.x = logf(a.x + b.x + EPS);
    v.y = logf(a.y + b.y + EPS);
    v.z = logf(a.z + b.z + EPS);
    v.w = logf(a.w + b.w + EPS);
    out4[i] = v;
  }
}

extern "C" void kernel_launch(void* const* d_in, const int* in_sizes, int n_in,
                              void* d_out, int out_size, void* d_ws, size_t ws_size,
                              hipStream_t stream)
{
  const float* inp = (const float*)d_in[0];
  const float* gw  = (const float*)d_in[1];
  const float* gb  = (const float*)d_in[2];
  const float* W1  = (const float*)d_in[3];
  const float* b1  = (const float*)d_in[4];
  const float* W2  = (const float*)d_in[5];
  const float* b2  = (const float*)d_in[6];
  float* out = (float*)d_out;

  char* ws = (char*)d_ws;
  size_t off = 0;
  auto alloc = [&](size_t bytes) {
    void* p = ws + off;
    off = (off + bytes + 255) & ~(size_t)255;
    return p;
  };
  // Xb (16 MB) and W1b (67 MB) are contiguous; both are dead after gemm1.
  // P (CAP*DDIM*4 = 71 MB) overlays them, written by gemm2 / read by combine.
  u16*   Xb  = (u16*)alloc((size_t)B_TOK * DDIM * 2);
  u16*   W1b = (u16*)alloc((size_t)NEXP * HDIM * DDIM * 2);
  float* P   = (float*)Xb;   // overlay: 71 MB <= 83 MB (Xb+W1b)
  u16*   W2b = (u16*)alloc((size_t)NEXP * DDIM * HDIM * 2);
  u16*   Hb  = (u16*)alloc((size_t)CAP * HDIM * 2);
  int*   slot_token = (int*)alloc(CAP * 4);
  float* slot_gate  = (float*)alloc(CAP * 4);
  int*   tok_e    = (int*)alloc(B_TOK * 2 * 4);
  float* tok_g    = (float*)alloc(B_TOK * 2 * 4);
  int*   tok_slot = (int*)alloc(B_TOK * 2 * 4);
  int*   counts  = (int*)alloc(32);
  int*   cursors = (int*)alloc(32);
  int*   offs    = (int*)alloc(32);
  int*   padded  = (int*)alloc(32);

  (void)hipMemsetAsync(counts, 0, 288, stream);                 // counts + cursors
  (void)hipMemsetAsync(slot_token, 0, (size_t)CAP * 8, stream); // slot_token + slot_gate

  gate_kernel<<<B_TOK / 4, 256, 0, stream>>>(inp, gw, gb, tok_e, tok_g, counts,
                                             (ushort4*)Xb);
  cvtw_kernel<<<2048, 256, 0, stream>>>(W1, W2, W1b, W2b);
  scatter_kernel<<<B_TOK / 256, 256, 0, stream>>>(tok_e, tok_g, counts, cursors,
                                                  slot_token, slot_gate, tok_slot,
                                                  offs, padded);

  gemm1_kernel<<<dim3(32, 64, NEXP), 256, 0, stream>>>(
      Xb, W1b, b1, slot_token, offs, padded, Hb);
  gemm2_kernel<<<dim3(8, 64, NEXP), 256, 0, stream>>>(
      Hb, W2b, b2, slot_gate, offs, padded, P);

  combine_kernel<<<2048, 256, 0, stream>>>((const float4*)P, tok_slot, (float4*)out);
}

// Round 24
// 694.108 us; speedup vs baseline: 1.0516x; 1.0516x over previous
//
#include <hip/hip_runtime.h>
#include <hip/hip_bf16.h>
#include <math.h>

#define B_TOK 8192
#define DDIM  1024
#define HDIM  4096
#define NEXP  8
#define CAP   17408   // 16384 routed pairs + 8*127 padding (128-tile)

typedef unsigned short u16;
using f32x4  = __attribute__((ext_vector_type(4))) float;
using bf16x8 = __attribute__((ext_vector_type(8))) short;  // 8 bf16 in 4 VGPRs
using u16x8  = __attribute__((ext_vector_type(8))) unsigned short;

__device__ __forceinline__ u16 f2bf(float f) {
  union { float f; unsigned u; } v; v.f = f;
  unsigned r = v.u + 0x7FFFu + ((v.u >> 16) & 1u);  // RNE
  return (u16)(r >> 16);
}

__device__ __forceinline__ void load_lds16(const void* g, void* l) {
  __builtin_amdgcn_global_load_lds((const __attribute__((address_space(1))) void*)g,
                                   (__attribute__((address_space(3))) void*)l,
                                   16, 0, 0);
}

// ==== prep: blocks [0,2048) = gating (+X->bf16);
//            blocks [2048,4096) = W1 cvt; [4096,6144) = W2 cvt ====
__global__ __launch_bounds__(256) void prep_kernel(
    const float* __restrict__ inp, const float* __restrict__ gw,
    const float* __restrict__ gb, int* __restrict__ tok_e,
    float* __restrict__ tok_g, int* __restrict__ counts,
    ushort4* __restrict__ Xb4,
    const float* __restrict__ w1, const float* __restrict__ w2,
    u16* __restrict__ w1b, u16* __restrict__ w2b, int n8each)
{
  if (blockIdx.x >= 2048) {
    const int wb   = blockIdx.x - 2048;
    const int half = wb >> 11;            // 0 -> W1, 1 -> W2
    const int lb   = wb & 2047;
    const f32x4* src = (const f32x4*)(half ? w2 : w1);
    u16x8*       dst = (u16x8*)(half ? w2b : w1b);
    const int tcnt = 2048 * 256;
    const int base = lb * 256 + threadIdx.x;
    for (int o = 0; o < n8each; o += 4 * tcnt) {
      f32x4 a[4][2];
#pragma unroll
      for (int k = 0; k < 4; ++k) {
        int i = base + o + k * tcnt;
        if (i < n8each) {
          a[k][0] = src[2 * i];
          a[k][1] = src[2 * i + 1];
        }
      }
#pragma unroll
      for (int k = 0; k < 4; ++k) {
        int i = base + o + k * tcnt;
        if (i < n8each) {
          u16x8 v;
          v[0] = f2bf(a[k][0][0]); v[1] = f2bf(a[k][0][1]);
          v[2] = f2bf(a[k][0][2]); v[3] = f2bf(a[k][0][3]);
          v[4] = f2bf(a[k][1][0]); v[5] = f2bf(a[k][1][1]);
          v[6] = f2bf(a[k][1][2]); v[7] = f2bf(a[k][1][3]);
          __builtin_nontemporal_store(v, &dst[i]);
        }
      }
    }
    return;
  }
  // ---- gating path: one wave per token, 4 tokens per block ----
  int gtid = blockIdx.x * 256 + threadIdx.x;
  int tok  = gtid >> 6;
  int lane = threadIdx.x & 63;
  if (tok >= B_TOK) return;
  const float4* X = (const float4*)(inp + (size_t)tok * DDIM);
  float4 x[4];
#pragma unroll
  for (int j = 0; j < 4; ++j) x[j] = X[j * 64 + lane];
  ushort4* Xrow = Xb4 + (size_t)tok * (DDIM / 4);
#pragma unroll
  for (int j = 0; j < 4; ++j) {
    ushort4 o;
    o.x = f2bf(x[j].x); o.y = f2bf(x[j].y); o.z = f2bf(x[j].z); o.w = f2bf(x[j].w);
    Xrow[j * 64 + lane] = o;
  }
  float lg[NEXP];
#pragma unroll
  for (int e = 0; e < NEXP; ++e) {
    const float4* W = (const float4*)(gw + e * DDIM);
    double s = 0.0;
#pragma unroll
    for (int j = 0; j < 4; ++j) {
      float4 w = W[j * 64 + lane];
      s += (double)x[j].x * w.x + (double)x[j].y * w.y
         + (double)x[j].z * w.z + (double)x[j].w * w.w;
    }
#pragma unroll
    for (int o = 32; o > 0; o >>= 1) s += __shfl_xor(s, o);
    lg[e] = (float)(s + (double)gb[e]);
  }
  if (lane == 0) {
    int i0 = 0; float v0 = lg[0];
#pragma unroll
    for (int e = 1; e < NEXP; ++e) if (lg[e] > v0) { v0 = lg[e]; i0 = e; }
    int i1 = -1; float v1 = -3.4e38f;
#pragma unroll
    for (int e = 0; e < NEXP; ++e) if (e != i0 && lg[e] > v1) { v1 = lg[e]; i1 = e; }
    float t   = __expf(v1 - v0);
    float inv = 1.0f / (1.0f + t);
    tok_e[2 * tok] = i0; tok_e[2 * tok + 1] = i1;
    tok_g[2 * tok] = inv; tok_g[2 * tok + 1] = t * inv;
    atomicAdd(&counts[i0], 1);
    atomicAdd(&counts[i1], 1);
  }
}

// -- scatter tokens into expert slots (scan fused; writes inverse map tok_slot) --
__global__ __launch_bounds__(256) void scatter_kernel(
    const int* __restrict__ tok_e, const float* __restrict__ tok_g,
    const int* __restrict__ counts, int* __restrict__ cursors,
    int* __restrict__ slot_token, float* __restrict__ slot_gate,
    int* __restrict__ tok_slot,
    int* __restrict__ offs, int* __restrict__ padded)
{
  __shared__ int soffs[NEXP];
  if (threadIdx.x == 0) {
    int off = 0;
    for (int e = 0; e < NEXP; ++e) {
      soffs[e] = off;
      int p = (counts[e] + 127) & ~127;
      off += p;
      if (blockIdx.x == 0) { offs[e] = soffs[e]; padded[e] = p; }
    }
  }
  __syncthreads();
  int b = blockIdx.x * 256 + threadIdx.x;
  if (b >= B_TOK) return;
#pragma unroll
  for (int k = 0; k < 2; ++k) {
    int e   = tok_e[2 * b + k];
    float g = tok_g[2 * b + k];
    int pos = atomicAdd(&cursors[e], 1);
    int s   = soffs[e] + pos;
    slot_token[s] = b;
    slot_gate[s]  = g;
    tok_slot[2 * b + k] = s;
  }
}

// ===== 128x128 x BK64, SINGLE LDS buffer, 8-slot XOR swizzle (bf16 weights) =====
#define STAGE(kt_) do {                                                   \
    _Pragma("unroll") for (int g = 0; g < 4; ++g) {                       \
      load_lds16(pAg[g] + (kt_) * 64, &As[(g * 256 + tid) * 8]);           \
      load_lds16(pBg[g] + (kt_) * 64, &Bs[(g * 256 + tid) * 8]);           \
    } } while (0)

#define GEMM_BODY(NT_) do {                                               \
    const int NT = (NT_);                                                 \
    _Pragma("unroll 1")                                                   \
    for (int t = 0; t < NT; ++t) {                                        \
      STAGE(t);                                                           \
      __syncthreads();                                                    \
      bf16x8 af[4][2], bfr[4][2];                                         \
      _Pragma("unroll") for (int m = 0; m < 4; ++m)                       \
        _Pragma("unroll") for (int kk = 0; kk < 2; ++kk)                  \
          af[m][kk] = *(const bf16x8*)&As[(wm + m*16 + fr)*64             \
                                        + (((kk*4 + fq) ^ fr7) * 8)];     \
      _Pragma("unroll") for (int n = 0; n < 4; ++n)                       \
        _Pragma("unroll") for (int kk = 0; kk < 2; ++kk)                  \
          bfr[n][kk] = *(const bf16x8*)&Bs[(wn + n*16 + fr)*64            \
                                        + (((kk*4 + fq) ^ fr7) * 8)];     \
      _Pragma("unroll") for (int kk = 0; kk < 2; ++kk)                    \
      _Pragma("unroll") for (int m = 0; m < 4; ++m)                       \
      _Pragma("unroll") for (int n = 0; n < 4; ++n)                       \
        acc[m][n] = __builtin_amdgcn_mfma_f32_16x16x32_bf16(              \
            af[m][kk], bfr[n][kk], acc[m][n], 0, 0, 0);                   \
      __syncthreads();                                                    \
    } } while (0)

// ---------------- GEMM1: h = relu(X_gather @ W1[e]^T + b1[e]) -> bf16 ----------------
__global__ __launch_bounds__(256, 4) void gemm1_kernel(
    const u16* __restrict__ Xb, const u16* __restrict__ W1b,
    const float* __restrict__ b1, const int* __restrict__ slot_token,
    const int* __restrict__ offs, const int* __restrict__ padded,
    u16* __restrict__ Hb)
{
  const int h   = blockIdx.x + 32 * (blockIdx.y + 64 * blockIdx.z);  // grid (32,64,8)
  const int e   = h & 7;          // XCD id == expert
  const int r   = h >> 3;
  const int mi  = r >> 5;         // m-tile [0,64)
  const int nti = r & 31;         // n-tile fastest within XCD
  if (mi * 128 >= padded[e]) return;
  const int base_slot = offs[e] + mi * 128;
  const int n0 = nti * 128;

  __shared__ __align__(16) u16 As[8192];   // 128 x 64
  __shared__ __align__(16) u16 Bs[8192];
  __shared__ int toks[128];

  const int tid = threadIdx.x;
  if (tid < 128) toks[tid] = slot_token[base_slot + tid];
  __syncthreads();

  const u16* pAg[4];
  const u16* pBg[4];
#pragma unroll
  for (int g = 0; g < 4; ++g) {
    int i = g * 256 + tid, rr = i >> 3, sl = i & 7;
    int kc = (sl ^ (rr & 7)) * 8;
    pAg[g] = Xb + (size_t)toks[rr] * DDIM + kc;
    pBg[g] = W1b + ((size_t)e * HDIM + (size_t)(n0 + rr)) * DDIM + kc;
  }

  const int wave = tid >> 6, lane = tid & 63;
  const int wm = (wave >> 1) * 64, wn = (wave & 1) * 64;
  const int fr = lane & 15, fq = lane >> 4, fr7 = fr & 7;

  f32x4 acc[4][4];
#pragma unroll
  for (int m = 0; m < 4; ++m)
#pragma unroll
    for (int n = 0; n < 4; ++n) acc[m][n] = f32x4{0.f, 0.f, 0.f, 0.f};

  GEMM_BODY(DDIM / 64);   // 16 bodies

#pragma unroll
  for (int n = 0; n < 4; ++n) {
    int col = n0 + wn + n * 16 + fr;
    float bias = b1[e * HDIM + col];
#pragma unroll
    for (int m = 0; m < 4; ++m) {
      int row0 = wm + m * 16 + fq * 4;
#pragma unroll
      for (int j = 0; j < 4; ++j) {
        float v = acc[m][n][j] + bias;
        v = v > 0.f ? v : 0.f;
        Hb[(size_t)(base_slot + row0 + j) * HDIM + col] = f2bf(v);
      }
    }
  }
}

// --- GEMM2: P[slot] = gate*exp(relu(H @ W2[e]^T + b2[e]))  (plain stores) ---
__global__ __launch_bounds__(256, 4) void gemm2_kernel(
    const u16* __restrict__ Hb, const u16* __restrict__ W2b,
    const float* __restrict__ b2, const float* __restrict__ slot_gate,
    const int* __restrict__ offs, const int* __restrict__ padded,
    float* __restrict__ P)
{
  const int h   = blockIdx.x + 8 * (blockIdx.y + 64 * blockIdx.z);  // grid (8,64,8)
  const int e   = h & 7;
  const int r   = h >> 3;
  const int mi  = r >> 3;         // m-tile [0,64)
  const int nti = r & 7;          // n-tile fastest within XCD
  if (mi * 128 >= padded[e]) return;
  const int base_slot = offs[e] + mi * 128;
  const int n0 = nti * 128;

  __shared__ __align__(16) u16 As[8192];
  __shared__ __align__(16) u16 Bs[8192];
  __shared__ float gts[128];

  const int tid = threadIdx.x;
  if (tid < 128) gts[tid] = slot_gate[base_slot + tid];
  __syncthreads();

  const u16* pAg[4];
  const u16* pBg[4];
#pragma unroll
  for (int g = 0; g < 4; ++g) {
    int i = g * 256 + tid, rr = i >> 3, sl = i & 7;
    int kc = (sl ^ (rr & 7)) * 8;
    pAg[g] = Hb + (size_t)(base_slot + rr) * HDIM + kc;
    pBg[g] = W2b + ((size_t)e * DDIM + (size_t)(n0 + rr)) * HDIM + kc;
  }

  const int wave = tid >> 6, lane = tid & 63;
  const int wm = (wave >> 1) * 64, wn = (wave & 1) * 64;
  const int fr = lane & 15, fq = lane >> 4, fr7 = fr & 7;

  f32x4 acc[4][4];
#pragma unroll
  for (int m = 0; m < 4; ++m)
#pragma unroll
    for (int n = 0; n < 4; ++n) acc[m][n] = f32x4{0.f, 0.f, 0.f, 0.f};

  GEMM_BODY(HDIM / 64);   // 64 bodies

#pragma unroll
  for (int n = 0; n < 4; ++n) {
    int col = n0 + wn + n * 16 + fr;
    float bias = b2[e * DDIM + col];
#pragma unroll
    for (int m = 0; m < 4; ++m) {
      int row0 = wm + m * 16 + fq * 4;
#pragma unroll
      for (int j = 0; j < 4; ++j) {
        int row = row0 + j;
        float v = acc[m][n][j] + bias;
        v = v > 0.f ? v : 0.f;
        P[(size_t)(base_slot + row) * DDIM + col] = gts[row] * __expf(v);
      }
    }
  }
}

// ------- combine: out[tok] = log(P[s0] + P[s1] + eps)  (fixed k-order sum) -------
__global__ __launch_bounds__(256) void combine_kernel(
    const float4* __restrict__ P4, const int* __restrict__ tok_slot,
    float4* __restrict__ out4)
{
  const float EPS = 2.220446049250313e-16f;
  const int total = B_TOK * (DDIM / 4);
  for (int i = blockIdx.x * 256 + threadIdx.x; i < total; i += gridDim.x * 256) {
    int tok = i >> 8, d4 = i & 255;
    int s0 = tok_slot[2 * tok], s1 = tok_slot[2 * tok + 1];
    float4 a = P4[(size_t)s0 * (DDIM / 4) + d4];
    float4 b = P4[(size_t)s1 * (DDIM / 4) + d4];
    float4 v;
    v.x = logf(a.x + b.x + EPS);
    v.y = logf(a.y + b.y + EPS);
    v.z = logf(a.z + b.z + EPS);
    v.w = logf(a.w + b.w + EPS);
    out4[i] = v;
  }
}

extern "C" void kernel_launch(void* const* d_in, const int* in_sizes, int n_in,
                              void* d_out, int out_size, void* d_ws, size_t ws_size,
                              hipStream_t stream)
{
  const float* inp = (const float*)d_in[0];
  const float* gw  = (const float*)d_in[1];
  const float* gb  = (const float*)d_in[2];
  const float* W1  = (const float*)d_in[3];
  const float* b1  = (const float*)d_in[4];
  const float* W2  = (const float*)d_in[5];
  const float* b2  = (const float*)d_in[6];
  float* out = (float*)d_out;

  char* ws = (char*)d_ws;
  size_t off = 0;
  auto alloc = [&](size_t bytes) {
    void* p = ws + off;
    off = (off + bytes + 255) & ~(size_t)255;
    return p;
  };
  // Xb (16 MB) and W1b (67 MB) are contiguous; both are dead after gemm1.
  // P (CAP*DDIM*4 = 71 MB) overlays them, written by gemm2 / read by combine.
  u16*   Xb  = (u16*)alloc((size_t)B_TOK * DDIM * 2);
  u16*   W1b = (u16*)alloc((size_t)NEXP * HDIM * DDIM * 2);
  float* P   = (float*)Xb;   // overlay: 71 MB <= 83 MB (Xb+W1b)
  u16*   W2b = (u16*)alloc((size_t)NEXP * DDIM * HDIM * 2);
  u16*   Hb  = (u16*)alloc((size_t)CAP * HDIM * 2);
  int*   slot_token = (int*)alloc(CAP * 4);
  float* slot_gate  = (float*)alloc(CAP * 4);
  int*   tok_e    = (int*)alloc(B_TOK * 2 * 4);
  float* tok_g    = (float*)alloc(B_TOK * 2 * 4);
  int*   tok_slot = (int*)alloc(B_TOK * 2 * 4);
  int*   counts  = (int*)alloc(32);
  int*   cursors = (int*)alloc(32);
  int*   offs    = (int*)alloc(32);
  int*   padded  = (int*)alloc(32);

  (void)hipMemsetAsync(counts, 0, 288, stream);                 // counts + cursors
  (void)hipMemsetAsync(slot_token, 0, (size_t)CAP * 8, stream); // slot_token + slot_gate

  // prep: gating (+X cvt) on [0,2048) ∥ W1 cvt on [2048,4096) ∥ W2 cvt on [4096,6144)
  prep_kernel<<<6144, 256, 0, stream>>>(inp, gw, gb, tok_e, tok_g, counts,
                                        (ushort4*)Xb,
                                        W1, W2, W1b, W2b,
                                        NEXP * HDIM * DDIM / 8);
  scatter_kernel<<<B_TOK / 256, 256, 0, stream>>>(tok_e, tok_g, counts, cursors,
                                                  slot_token, slot_gate, tok_slot,
                                                  offs, padded);

  gemm1_kernel<<<dim3(32, 64, NEXP), 256, 0, stream>>>(
      Xb, W1b, b1, slot_token, offs, padded, Hb);
  gemm2_kernel<<<dim3(8, 64, NEXP), 256, 0, stream>>>(
      Hb, W2b, b2, slot_gate, offs, padded, P);

  combine_kernel<<<2048, 256, 0, stream>>>((const float4*)P, tok_slot, (float4*)out);
}